// Round 11
// baseline (268.294 us; speedup 1.0000x reference)
//
#include <hip/hip_runtime.h>
#include <type_traits>

typedef __attribute__((ext_vector_type(8))) short short8;
typedef __attribute__((ext_vector_type(8))) unsigned short ushort8;
typedef __attribute__((ext_vector_type(4))) float floatx4;
typedef __attribute__((ext_vector_type(2))) unsigned int uintx2v;

__device__ __forceinline__ unsigned short f2bf(float f) {
    union { float f; unsigned int i; } v;
    v.f = f;
    unsigned int u = v.i;
    unsigned int r = (u + 0x7FFFu + ((u >> 16) & 1u)) >> 16;
    return (unsigned short)r;
}

// async global->LDS, 16B per lane; global addr per-lane, LDS dest = uniform base + lane*16
__device__ __forceinline__ void gload_lds16(const unsigned short* g, unsigned short* lds_base) {
    __builtin_amdgcn_global_load_lds(
        (const __attribute__((address_space(1))) unsigned int*)g,
        (__attribute__((address_space(3))) unsigned int*)lds_base,
        16, 0, 0);
}

// compiler-fenced raw barrier (no vmcnt(0) drain, unlike __syncthreads)
__device__ __forceinline__ void pbar() {
    asm volatile("" ::: "memory");
    __builtin_amdgcn_s_barrier();
    asm volatile("" ::: "memory");
}

// fp32 -> bf16 (RNE), 8 elems/thread
__global__ __launch_bounds__(256) void cvt_f32_bf16_kernel(
    const float* __restrict__ src, unsigned short* __restrict__ dst, int n8)
{
    int i = blockIdx.x * 256 + threadIdx.x;
    if (i >= n8) return;
    const float4* s = (const float4*)src + (size_t)i * 2;
    float4 a = s[0];
    float4 b = s[1];
    ushort8 r;
    r[0] = f2bf(a.x); r[1] = f2bf(a.y); r[2] = f2bf(a.z); r[3] = f2bf(a.w);
    r[4] = f2bf(b.x); r[5] = f2bf(b.y); r[6] = f2bf(b.z); r[7] = f2bf(b.w);
    *((ushort8*)dst + i) = r;
}

// W [K][N] fp32  ->  Wt [N][K] bf16 (fused transpose+convert), 32x32 tiles
__global__ __launch_bounds__(256) void transpose_cvt_kernel(
    const float* __restrict__ src, unsigned short* __restrict__ dst, int K, int N)
{
    __shared__ float tile[32][33];
    const int tx = threadIdx.x & 31;
    const int ty = threadIdx.x >> 5;  // 0..7
    const int k0 = blockIdx.y * 32, n0 = blockIdx.x * 32;
#pragma unroll
    for (int i = 0; i < 4; ++i)
        tile[ty + i * 8][tx] = src[(size_t)(k0 + ty + i * 8) * N + n0 + tx];
    __syncthreads();
#pragma unroll
    for (int i = 0; i < 4; ++i)
        dst[(size_t)(n0 + ty + i * 8) * K + k0 + tx] = f2bf(tile[tx][ty + i * 8]);
}

// 256x256 8-phase GEMM (m201-style, T3+T5): C = A[M,K] @ Bt[N,K]^T + bias.
// 512 threads = 8 waves (2M x 4N), wave tile 128x64, BK=64, nt = K/64.
// LDS: 2 whole-tile buffers, [row 0..255][8 units of 16B] with slot-XOR
// swizzle: unit k of row r stored at slot k ^ (r&7).
//  - staging (r2 lesson FIXED): linear LDS dest; instr i covers rows
//    i*64+(tid>>3), slot tid&7 -> source kc-unit (tid&7)^((tid>>3)&7):
//    each row read as one contiguous 128B segment (8 lanes) -> full
//    coalescing, 1KB/instr, 4 instrs per operand per K-tile per wave.
//  - fragment read: slot = (ks*4+quad) ^ (l16&7); quarter-wave covers all
//    8 bank-groups exactly 2x -> conflict-free.
// Schedule per K-tile t (buf b=t&1), 4 phases x 16 MFMA:
//   ph0: read bfr[4][2] (8) + A mi0-1 (4); issue STA(t+1) x4
//   ph1: read A mi2-3; issue STB(t+1) x4     (all 8 loads >=1200cy early)
//   ph2: read A mi4-5
//   ph3: read A mi6-7; after MFMA: vmcnt(0) (t+1 landed), barrier.
//   Each phase: barrier; lgkmcnt(0); setprio(1); 16 MFMA; setprio(0); barrier.
// MODE 0: plain C[m][n]. MODE 1: qkv split epilogue.
template <int MODE, typename OutT>
__global__ __launch_bounds__(512, 2) void gemm256_kernel(
    const unsigned short* __restrict__ A,
    const unsigned short* __restrict__ Bt,
    const float* __restrict__ bias,
    OutT* __restrict__ C,
    unsigned short* __restrict__ Qo,
    unsigned short* __restrict__ Ko,
    unsigned short* __restrict__ Vto,
    int M, int N, int K)
{
    __shared__ __align__(16) unsigned short As[2][256 * 64];  // 2x32KB, slot-swizzled
    __shared__ __align__(16) unsigned short Bs[2][256 * 64];  // 2x32KB

    const int tid  = threadIdx.x;
    const int lane = tid & 63;
    const int w    = tid >> 6;       // 0..7
    const int wm   = w >> 2;         // 0..1 (M half)
    const int wn   = w & 3;          // 0..3 (N quarter)
    const int quad = lane >> 4;
    const int l16  = lane & 15;

    const int m0 = blockIdx.y * 256;
    const int n0 = blockIdx.x * 256;

    floatx4 acc[8][4];
#pragma unroll
    for (int i = 0; i < 8; ++i)
#pragma unroll
        for (int j = 0; j < 4; ++j) acc[i][j] = (floatx4)0.0f;

    // staging source: instr i covers rows i*64 + (tid>>3), swizzle-inverse kc
    const int srow = tid >> 3;                                   // 0..63
    const int skc  = (((tid & 7) ^ ((tid >> 3) & 7)) << 3);      // elems
    const unsigned short* Ag = A  + (size_t)(m0 + srow) * K + skc;
    const unsigned short* Bg = Bt + (size_t)(n0 + srow) * K + skc;

    const int swz = l16 & 7;   // fragment-read row phase

    const int nt = K >> 6;

#define STA(buf, t, i) gload_lds16(Ag + (size_t)((i) * 64) * K + (t) * 64, &As[buf][(i) * 4096 + w * 512])
#define STB(buf, t, i) gload_lds16(Bg + (size_t)((i) * 64) * K + (t) * 64, &Bs[buf][(i) * 4096 + w * 512])
#define ASLOT(ks) ((((ks) * 4 + quad) ^ swz) << 3)

    // prologue: tile 0 -> buf 0
#pragma unroll
    for (int i = 0; i < 4; ++i) STA(0, 0, i);
#pragma unroll
    for (int i = 0; i < 4; ++i) STB(0, 0, i);
    asm volatile("s_waitcnt vmcnt(0)" ::: "memory");
    pbar();

    for (int t = 0; t < nt; ++t) {
        const int b = t & 1;
        const unsigned short* Ab = &As[b][0];
        const unsigned short* Bb = &Bs[b][0];

        // ---------- phase 0: B all + A mi0-1; stage A(t+1) ----------
        short8 bfr[4][2], af[2][2];
#pragma unroll
        for (int ni = 0; ni < 4; ++ni)
#pragma unroll
            for (int ks = 0; ks < 2; ++ks)
                bfr[ni][ks] = *(const short8*)&Bb[(wn * 64 + ni * 16 + l16) * 64 + ASLOT(ks)];
#pragma unroll
        for (int x = 0; x < 2; ++x)
#pragma unroll
            for (int ks = 0; ks < 2; ++ks)
                af[x][ks] = *(const short8*)&Ab[(wm * 128 + x * 16 + l16) * 64 + ASLOT(ks)];
        if (t + 1 < nt) {
#pragma unroll
            for (int i = 0; i < 4; ++i) STA(b ^ 1, t + 1, i);
        }
        pbar();
        asm volatile("s_waitcnt lgkmcnt(0)" ::: "memory");
        __builtin_amdgcn_s_setprio(1);
#pragma unroll
        for (int x = 0; x < 2; ++x)
#pragma unroll
            for (int ni = 0; ni < 4; ++ni)
#pragma unroll
                for (int ks = 0; ks < 2; ++ks)
                    acc[x][ni] = __builtin_amdgcn_mfma_f32_16x16x32_bf16(af[x][ks], bfr[ni][ks], acc[x][ni], 0, 0, 0);
        __builtin_amdgcn_s_setprio(0);
        pbar();

        // ---------- phase 1: A mi2-3; stage B(t+1) ----------
#pragma unroll
        for (int x = 0; x < 2; ++x)
#pragma unroll
            for (int ks = 0; ks < 2; ++ks)
                af[x][ks] = *(const short8*)&Ab[(wm * 128 + (2 + x) * 16 + l16) * 64 + ASLOT(ks)];
        if (t + 1 < nt) {
#pragma unroll
            for (int i = 0; i < 4; ++i) STB(b ^ 1, t + 1, i);
        }
        pbar();
        asm volatile("s_waitcnt lgkmcnt(0)" ::: "memory");
        __builtin_amdgcn_s_setprio(1);
#pragma unroll
        for (int x = 0; x < 2; ++x)
#pragma unroll
            for (int ni = 0; ni < 4; ++ni)
#pragma unroll
                for (int ks = 0; ks < 2; ++ks)
                    acc[2 + x][ni] = __builtin_amdgcn_mfma_f32_16x16x32_bf16(af[x][ks], bfr[ni][ks], acc[2 + x][ni], 0, 0, 0);
        __builtin_amdgcn_s_setprio(0);
        pbar();

        // ---------- phase 2: A mi4-5 ----------
#pragma unroll
        for (int x = 0; x < 2; ++x)
#pragma unroll
            for (int ks = 0; ks < 2; ++ks)
                af[x][ks] = *(const short8*)&Ab[(wm * 128 + (4 + x) * 16 + l16) * 64 + ASLOT(ks)];
        pbar();
        asm volatile("s_waitcnt lgkmcnt(0)" ::: "memory");
        __builtin_amdgcn_s_setprio(1);
#pragma unroll
        for (int x = 0; x < 2; ++x)
#pragma unroll
            for (int ni = 0; ni < 4; ++ni)
#pragma unroll
                for (int ks = 0; ks < 2; ++ks)
                    acc[4 + x][ni] = __builtin_amdgcn_mfma_f32_16x16x32_bf16(af[x][ks], bfr[ni][ks], acc[4 + x][ni], 0, 0, 0);
        __builtin_amdgcn_s_setprio(0);
        pbar();

        // ---------- phase 3: A mi6-7; vmcnt(0) -> tile t+1 confirmed ----------
#pragma unroll
        for (int x = 0; x < 2; ++x)
#pragma unroll
            for (int ks = 0; ks < 2; ++ks)
                af[x][ks] = *(const short8*)&Ab[(wm * 128 + (6 + x) * 16 + l16) * 64 + ASLOT(ks)];
        pbar();
        asm volatile("s_waitcnt lgkmcnt(0)" ::: "memory");
        __builtin_amdgcn_s_setprio(1);
#pragma unroll
        for (int x = 0; x < 2; ++x)
#pragma unroll
            for (int ni = 0; ni < 4; ++ni)
#pragma unroll
                for (int ks = 0; ks < 2; ++ks)
                    acc[6 + x][ni] = __builtin_amdgcn_mfma_f32_16x16x32_bf16(af[x][ks], bfr[ni][ks], acc[6 + x][ni], 0, 0, 0);
        __builtin_amdgcn_s_setprio(0);
        asm volatile("s_waitcnt vmcnt(0)" ::: "memory");
        pbar();
    }
#undef STA
#undef STB
#undef ASLOT

    // epilogue. C/D layout: col (n) = l16, row (m) = quad*4 + r
#pragma unroll
    for (int ni = 0; ni < 4; ++ni) {
        const int n = n0 + wn * 64 + ni * 16 + l16;
        const float bval = bias[n];
        const int seg = n >> 10;       // uniform per block (256 | 1024)
        const int nl  = n & 1023;
#pragma unroll
        for (int mi = 0; mi < 8; ++mi) {
            if constexpr (MODE == 0) {
#pragma unroll
                for (int r = 0; r < 4; ++r) {
                    const int m = m0 + wm * 128 + mi * 16 + (quad << 2) + r;
                    const float val = acc[mi][ni][r] + bval;
                    if constexpr (std::is_same<OutT, unsigned short>::value)
                        C[(size_t)m * N + n] = f2bf(val);
                    else
                        C[(size_t)m * N + n] = val;
                }
            } else {
                if (seg < 2) {
                    unsigned short* P = (seg == 0) ? Qo : Ko;
#pragma unroll
                    for (int r = 0; r < 4; ++r) {
                        const int m = m0 + wm * 128 + mi * 16 + (quad << 2) + r;
                        P[(size_t)m * 1024 + nl] = f2bf(acc[mi][ni][r] + bval);
                    }
                } else {
                    // V: 4 consecutive t -> one dwordx2 store
                    const int mb = m0 + wm * 128 + mi * 16 + (quad << 2);
                    const int bbk = mb >> 11, t0 = mb & 2047;
                    unsigned int lo = (unsigned int)f2bf(acc[mi][ni][0] + bval) |
                                      ((unsigned int)f2bf(acc[mi][ni][1] + bval) << 16);
                    unsigned int hi = (unsigned int)f2bf(acc[mi][ni][2] + bval) |
                                      ((unsigned int)f2bf(acc[mi][ni][3] + bval) << 16);
                    uint2 pv; pv.x = lo; pv.y = hi;
                    *(uint2*)(Vto + ((size_t)bbk * 1024 + nl) * 2048 + t0) = pv;
                }
            }
        }
    }
}

// softmax + bf16-pack + in-register P redistribution for one 16-q-row sub.
__device__ __forceinline__ void softmax_pack(
    const floatx4* s, bool masked, int key0, int qg, int kq4,
    float& l_run, short8& pf0o, short8& pf1o)
{
    const float SC2 = 0.18033688011112042f;    // 0.125*log2(e)
    const float MB2 = -17.312340490667562f;    // -12*log2(e)
    unsigned int plo[4], phi[4];
    if (!masked) {
#pragma unroll
        for (int ks = 0; ks < 4; ++ks) {
            float pv0 = __builtin_amdgcn_exp2f(fmaf(s[ks][0], SC2, MB2));
            float pv1 = __builtin_amdgcn_exp2f(fmaf(s[ks][1], SC2, MB2));
            float pv2 = __builtin_amdgcn_exp2f(fmaf(s[ks][2], SC2, MB2));
            float pv3 = __builtin_amdgcn_exp2f(fmaf(s[ks][3], SC2, MB2));
            l_run += (pv0 + pv1) + (pv2 + pv3);
            asm("v_cvt_pk_bf16_f32 %0, %1, %2" : "=v"(plo[ks]) : "v"(pv0), "v"(pv1));
            asm("v_cvt_pk_bf16_f32 %0, %1, %2" : "=v"(phi[ks]) : "v"(pv2), "v"(pv3));
        }
    } else {
#pragma unroll
        for (int ks = 0; ks < 4; ++ks) {
            const int kb = key0 + (ks << 4) + kq4;
            float a0 = (kb + 0 <= qg) ? fmaf(s[ks][0], SC2, MB2) : -100000.0f;
            float a1 = (kb + 1 <= qg) ? fmaf(s[ks][1], SC2, MB2) : -100000.0f;
            float a2 = (kb + 2 <= qg) ? fmaf(s[ks][2], SC2, MB2) : -100000.0f;
            float a3 = (kb + 3 <= qg) ? fmaf(s[ks][3], SC2, MB2) : -100000.0f;
            float pv0 = __builtin_amdgcn_exp2f(a0);
            float pv1 = __builtin_amdgcn_exp2f(a1);
            float pv2 = __builtin_amdgcn_exp2f(a2);
            float pv3 = __builtin_amdgcn_exp2f(a3);
            l_run += (pv0 + pv1) + (pv2 + pv3);
            asm("v_cvt_pk_bf16_f32 %0, %1, %2" : "=v"(plo[ks]) : "v"(pv0), "v"(pv1));
            asm("v_cvt_pk_bf16_f32 %0, %1, %2" : "=v"(phi[ks]) : "v"(pv2), "v"(pv3));
        }
    }
    uintx2v t0 = __builtin_amdgcn_permlane32_swap(plo[0], plo[1], false, false);
    uintx2v u0 = __builtin_amdgcn_permlane16_swap(t0[0], t0[1], false, false);
    uintx2v t1 = __builtin_amdgcn_permlane32_swap(phi[0], phi[1], false, false);
    uintx2v u1 = __builtin_amdgcn_permlane16_swap(t1[0], t1[1], false, false);
    uintx2v t2 = __builtin_amdgcn_permlane32_swap(plo[2], plo[3], false, false);
    uintx2v u2 = __builtin_amdgcn_permlane16_swap(t2[0], t2[1], false, false);
    uintx2v t3 = __builtin_amdgcn_permlane32_swap(phi[2], phi[3], false, false);
    uintx2v u3 = __builtin_amdgcn_permlane16_swap(t3[0], t3[1], false, false);
    union { unsigned int d[4]; short8 v; } fa, fb;
    fa.d[0] = u0[0]; fa.d[1] = u1[0]; fa.d[2] = u0[1]; fa.d[3] = u1[1];
    fb.d[0] = u2[0]; fb.d[1] = u3[0]; fb.d[2] = u2[1]; fb.d[3] = u3[1];
    pf0o = fa.v;
    pf1o = fb.v;
}

// Flash attention (r9 structure, unchanged): 128 q-rows/block, 2x16-row subs
// per wave sharing K/V fragment registers; single-buffer 16KB LDS; balanced
// qt' permutation; fully-masked tiles skip compute.
__global__ __launch_bounds__(256, 4) void attn_kernel(
    const unsigned short* __restrict__ Q,
    const unsigned short* __restrict__ Kq,
    const unsigned short* __restrict__ Vt,
    unsigned short* __restrict__ Y)
{
    const int T = 2048;

    int idx = blockIdx.x;
    int g   = idx >> 6;              // 0..15 (16 q-tiles of 128 rows)
    int qtp = (g & 4) ? ((g & 8) ? (g - 8) : (g - 4))
                      : ((g & 8) ? (19 - g) : (15 - g));
    int bh  = idx & 63;
    int b   = bh >> 4;
    int h   = bh & 15;

    const int tid  = threadIdx.x;
    const int lane = tid & 63;
    const int w    = tid >> 6;
    const int quad = lane >> 4;
    const int l16  = lane & 15;

    __shared__ __align__(16) unsigned short Ks2[8 * 64 * 8];   // 8KB
    __shared__ __align__(16) unsigned short Vs2[8 * 64 * 8];   // 8KB

    const int qb = qtp * 128 + (w << 5);     // wave's first q row

    const unsigned short* qpa = Q + (size_t)(b * T + qb + l16) * 1024 + h * 64;
    const unsigned short* qpb = qpa + (size_t)16 * 1024;
    short8 qfa0 = *(const short8*)(qpa + (quad << 3));
    short8 qfa1 = *(const short8*)(qpa + 32 + (quad << 3));
    short8 qfb0 = *(const short8*)(qpb + (quad << 3));
    short8 qfb1 = *(const short8*)(qpb + 32 + (quad << 3));

    float lra = 0.0f, lrb = 0.0f;
    floatx4 oa[4], ob[4];
#pragma unroll
    for (int ns = 0; ns < 4; ++ns) { oa[ns] = (floatx4)0.0f; ob[ns] = (floatx4)0.0f; }

    const unsigned short* kg0p = Kq + (size_t)(b * T + lane) * 1024 + h * 64 + (w) * 8;
    const unsigned short* kg1p = Kq + (size_t)(b * T + lane) * 1024 + h * 64 + (w + 4) * 8;
    const unsigned short* vg0p = Vt + ((size_t)(b * 1024 + h * 64 + lane)) * 2048 + (w) * 8;
    const unsigned short* vg1p = Vt + ((size_t)(b * 1024 + h * 64 + lane)) * 2048 + (w + 4) * 8;

    const int qa_g = qb + l16;        // sub-a lane q
    const int qb_g = qb + 16 + l16;   // sub-b lane q
    const int kq4  = quad << 2;

    const int ktiles = 2 * qtp + 2;
    for (int kt = 0; kt < ktiles; ++kt) {
        const int key0 = kt << 6;
        __syncthreads();
        gload_lds16(kg0p + (size_t)key0 * 1024, Ks2 + (w) * 512);
        gload_lds16(kg1p + (size_t)key0 * 1024, Ks2 + (w + 4) * 512);
        gload_lds16(vg0p + key0, Vs2 + (w) * 512);
        gload_lds16(vg1p + key0, Vs2 + (w + 4) * 512);
        __syncthreads();

        if (key0 <= qb + 31) {         // wave-uniform: skip fully-masked tiles
            floatx4 sa[4], sb[4];
#pragma unroll
            for (int ks = 0; ks < 4; ++ks) {
                short8 kf0 = *(const short8*)&Ks2[((0 * 4 + quad) * 64 + ks * 16 + l16) * 8];
                short8 kf1 = *(const short8*)&Ks2[((1 * 4 + quad) * 64 + ks * 16 + l16) * 8];
                sa[ks] = __builtin_amdgcn_mfma_f32_16x16x32_bf16(kf0, qfa0, (floatx4)0.0f, 0, 0, 0);
                sa[ks] = __builtin_amdgcn_mfma_f32_16x16x32_bf16(kf1, qfa1, sa[ks], 0, 0, 0);
                sb[ks] = __builtin_amdgcn_mfma_f32_16x16x32_bf16(kf0, qfb0, (floatx4)0.0f, 0, 0, 0);
                sb[ks] = __builtin_amdgcn_mfma_f32_16x16x32_bf16(kf1, qfb1, sb[ks], 0, 0, 0);
            }

            const bool masked = (key0 + 64 > qb);   // wave-uniform
            short8 pa0, pa1, pb0, pb1;
            softmax_pack(sa, masked, key0, qa_g, kq4, lra, pa0, pa1);
            softmax_pack(sb, masked, key0, qb_g, kq4, lrb, pb0, pb1);

#pragma unroll
            for (int ns = 0; ns < 4; ++ns) {
                short8 vf0 = *(const short8*)&Vs2[((0 * 4 + quad) * 64 + ns * 16 + l16) * 8];
                short8 vf1 = *(const short8*)&Vs2[((1 * 4 + quad) * 64 + ns * 16 + l16) * 8];
                oa[ns] = __builtin_amdgcn_mfma_f32_16x16x32_bf16(pa0, vf0, oa[ns], 0, 0, 0);
                oa[ns] = __builtin_amdgcn_mfma_f32_16x16x32_bf16(pa1, vf1, oa[ns], 0, 0, 0);
                ob[ns] = __builtin_amdgcn_mfma_f32_16x16x32_bf16(pb0, vf0, ob[ns], 0, 0, 0);
                ob[ns] = __builtin_amdgcn_mfma_f32_16x16x32_bf16(pb1, vf1, ob[ns], 0, 0, 0);
            }
        }
    }

    float sa_ = lra;
    sa_ += __shfl_xor(sa_, 16, 64);
    sa_ += __shfl_xor(sa_, 32, 64);
    const float lia = 1.0f / sa_;
    float sb_ = lrb;
    sb_ += __shfl_xor(sb_, 16, 64);
    sb_ += __shfl_xor(sb_, 32, 64);
    const float lib = 1.0f / sb_;

    float la[4], lb[4];
#pragma unroll
    for (int r = 0; r < 4; ++r) {
        la[r] = __shfl(lia, (quad << 2) + r, 64);
        lb[r] = __shfl(lib, (quad << 2) + r, 64);
    }

#pragma unroll
    for (int ns = 0; ns < 4; ++ns) {
        int d = (ns << 4) + l16;
#pragma unroll
        for (int r = 0; r < 4; ++r) {
            int ta = qb + (quad << 2) + r;
            Y[(size_t)(b * T + ta) * 1024 + h * 64 + d]        = f2bf(oa[ns][r] * la[r]);
            Y[(size_t)(b * T + ta + 16) * 1024 + h * 64 + d]   = f2bf(ob[ns][r] * lb[r]);
        }
    }
}

extern "C" void kernel_launch(void* const* d_in, const int* in_sizes, int n_in,
                              void* d_out, int out_size, void* d_ws, size_t ws_size,
                              hipStream_t stream) {
    const float* x  = (const float*)d_in[0];  // [4,2048,1024] fp32
    const float* Wa = (const float*)d_in[1];  // [1024,3072]  fp32
    const float* ba = (const float*)d_in[2];  // [3072]       fp32
    const float* Wp = (const float*)d_in[3];  // [1024,1024]  fp32
    const float* bp = (const float*)d_in[4];  // [1024]       fp32
    float* out = (float*)d_out;               // [4,2048,1024] fp32

    const size_t NX = (size_t)8192 * 1024;

    unsigned short* Qb  = (unsigned short*)d_ws;         // 8192*1024
    unsigned short* Kb  = Qb  + NX;                      // 8192*1024
    unsigned short* Vtb = Kb  + NX;                      // 4096*2048 = 8192*1024
    unsigned short* Yb  = Vtb + NX;                      // 8192*1024
    unsigned short* xb  = Yb  + NX;                      // 8192*1024
    unsigned short* Wat = xb  + NX;                      // 3072*1024 (N-major)
    unsigned short* Wpt = Wat + (size_t)3072 * 1024;     // 1024*1024

    // 0) convert x; transpose+convert weights to [N][K] bf16
    cvt_f32_bf16_kernel<<<(int)(NX / 8 / 256), 256, 0, stream>>>(x, xb, (int)(NX / 8));
    transpose_cvt_kernel<<<dim3(3072 / 32, 1024 / 32), 256, 0, stream>>>(Wa, Wat, 1024, 3072);
    transpose_cvt_kernel<<<dim3(1024 / 32, 1024 / 32), 256, 0, stream>>>(Wp, Wpt, 1024, 1024);

    // 1) qkv = x @ W_attn + b_attn -> Q,K ([m][1024]) and V transposed ([b*1024+d][2048])
    gemm256_kernel<1, unsigned short><<<dim3(3072 / 256, 8192 / 256), 512, 0, stream>>>(
        xb, Wat, ba, (unsigned short*)nullptr, Qb, Kb, Vtb, 8192, 3072, 1024);

    // 2) flash attention -> Y [B,T,C] bf16 (128-q-row blocks, 2 subs/wave)
    attn_kernel<<<4 * 16 * (2048 / 128), 256, 0, stream>>>(Qb, Kb, Vtb, Yb);

    // 3) out = Y @ W_proj + b_proj (fp32)
    gemm256_kernel<0, float><<<dim3(1024 / 256, 8192 / 256), 512, 0, stream>>>(
        Yb, Wpt, bp, out, nullptr, nullptr, nullptr, 8192, 1024, 1024);
}

// Round 12
// 245.394 us; speedup vs baseline: 1.0933x; 1.0933x over previous
//
#include <hip/hip_runtime.h>
#include <type_traits>

typedef __attribute__((ext_vector_type(8))) short short8;
typedef __attribute__((ext_vector_type(8))) unsigned short ushort8;
typedef __attribute__((ext_vector_type(4))) float floatx4;
typedef __attribute__((ext_vector_type(2))) unsigned int uintx2v;

__device__ __forceinline__ unsigned short f2bf(float f) {
    union { float f; unsigned int i; } v;
    v.f = f;
    unsigned int u = v.i;
    unsigned int r = (u + 0x7FFFu + ((u >> 16) & 1u)) >> 16;
    return (unsigned short)r;
}

// async global->LDS, 16B per lane; global addr per-lane, LDS dest = uniform base + lane*16
__device__ __forceinline__ void gload_lds16(const unsigned short* g, unsigned short* lds_base) {
    __builtin_amdgcn_global_load_lds(
        (const __attribute__((address_space(1))) unsigned int*)g,
        (__attribute__((address_space(3))) unsigned int*)lds_base,
        16, 0, 0);
}

// compiler-fenced raw barrier (no vmcnt(0) drain, unlike __syncthreads)
__device__ __forceinline__ void pbar() {
    asm volatile("" ::: "memory");
    __builtin_amdgcn_s_barrier();
    asm volatile("" ::: "memory");
}

// fp32 -> bf16 (RNE), 8 elems/thread
__global__ __launch_bounds__(256) void cvt_f32_bf16_kernel(
    const float* __restrict__ src, unsigned short* __restrict__ dst, int n8)
{
    int i = blockIdx.x * 256 + threadIdx.x;
    if (i >= n8) return;
    const float4* s = (const float4*)src + (size_t)i * 2;
    float4 a = s[0];
    float4 b = s[1];
    ushort8 r;
    r[0] = f2bf(a.x); r[1] = f2bf(a.y); r[2] = f2bf(a.z); r[3] = f2bf(a.w);
    r[4] = f2bf(b.x); r[5] = f2bf(b.y); r[6] = f2bf(b.z); r[7] = f2bf(b.w);
    *((ushort8*)dst + i) = r;
}

// W [K][N] fp32  ->  Wt [N][K] bf16 (fused transpose+convert), 32x32 tiles
__global__ __launch_bounds__(256) void transpose_cvt_kernel(
    const float* __restrict__ src, unsigned short* __restrict__ dst, int K, int N)
{
    __shared__ float tile[32][33];
    const int tx = threadIdx.x & 31;
    const int ty = threadIdx.x >> 5;  // 0..7
    const int k0 = blockIdx.y * 32, n0 = blockIdx.x * 32;
#pragma unroll
    for (int i = 0; i < 4; ++i)
        tile[ty + i * 8][tx] = src[(size_t)(k0 + ty + i * 8) * N + n0 + tx];
    __syncthreads();
#pragma unroll
    for (int i = 0; i < 4; ++i)
        dst[(size_t)(n0 + ty + i * 8) * K + k0 + tx] = f2bf(tile[tx][ty + i * 8]);
}

// m97-style GEMM + 2-tile-deep ring + SINGLE barrier per K-step.
// C = A[M,K] @ Bt[N,K]^T + bias. 128x128 tile, BK=32, 4 waves 2x2,
// each wave 4x4 16x16x32 MFMA tiles. LDS: 3-buffer ring [3][128][32]
// per operand (48KB), slot-XOR swizzle (r4: conflicts 0, contiguous
// 64B/row staging coalescing).
// r12 schedule (single-barrier; r10 had 2/step):
//   iter t: s_waitcnt vmcnt(4) [oldest-first -> tile t's 4 loads done;
//           stage(t+1) may remain in flight]; vmcnt(0) at t==nt-1;
//   s_barrier  -- publishes tile t AND proves all waves finished their
//           iter t-1 ds_reads (consumed by t-1 MFMAs via lgkmcnt before
//           the wave could reach this barrier);
//   stage(t+2) -> buf (t+2)%3 == buf (t-1)%3 (safe post-barrier);
//   ds_read frags(buf t%3); MFMA.  No trailing barrier.
// Prologue stages t=0,1 (8 outstanding).
template <int MODE, typename OutT>
__global__ __launch_bounds__(256) void gemm128_kernel(
    const unsigned short* __restrict__ A,
    const unsigned short* __restrict__ Bt,
    const float* __restrict__ bias,
    OutT* __restrict__ C,
    unsigned short* __restrict__ Qo,
    unsigned short* __restrict__ Ko,
    unsigned short* __restrict__ Vto,
    int M, int N, int K)
{
    __shared__ __align__(16) unsigned short As[3][128 * 32];  // slot-swizzled, 3x8KB
    __shared__ __align__(16) unsigned short Bs[3][128 * 32];  // slot-swizzled, 3x8KB

    const int tid  = threadIdx.x;
    const int lane = tid & 63;
    const int w    = tid >> 6;
    const int wm   = w & 1;
    const int wn   = w >> 1;
    const int quad = lane >> 4;
    const int l16  = lane & 15;

    const int m0 = blockIdx.y * 128;
    const int n0 = blockIdx.x * 128;

    floatx4 acc[4][4];
#pragma unroll
    for (int i = 0; i < 4; ++i)
#pragma unroll
        for (int j = 0; j < 4; ++j) acc[i][j] = (floatx4)0.0f;

    // staging: lane L writes LDS unit base+L (linear); source k-chunk is the
    // swizzle-inverse so (row,kc) lands at slot kc^((row>>1)&3).
    const int r0 = tid >> 2;          // 0..63
    const int kc = (((tid & 3) ^ ((tid >> 3) & 3)) << 3);
    const unsigned short* Ag = A  + (size_t)(m0 + r0) * K + kc;
    const unsigned short* Bg = Bt + (size_t)(n0 + r0) * K + kc;

    // fragment-read slot (row = ...*16 + l16 -> (row>>1)&3 == (l16>>1)&3)
    const int sw = ((quad ^ ((l16 >> 1) & 3)) << 3);

    const int nt = K >> 5;

#define STAGE(buf, t)                                                          \
    do {                                                                       \
        const int kk = (t) << 5;                                               \
        gload_lds16(Ag + kk,                    &As[buf][w * 512]);            \
        gload_lds16(Ag + (size_t)64 * K + kk,   &As[buf][w * 512 + 2048]);     \
        gload_lds16(Bg + kk,                    &Bs[buf][w * 512]);            \
        gload_lds16(Bg + (size_t)64 * K + kk,   &Bs[buf][w * 512 + 2048]);     \
    } while (0)

    STAGE(0, 0);   // prologue: 2 tiles in flight
    STAGE(1, 1);

    int bcur = 0, bst = 2;
    for (int t = 0; t < nt; ++t) {
        if (t < nt - 1) {
            asm volatile("s_waitcnt vmcnt(4)" ::: "memory");
        } else {
            asm volatile("s_waitcnt vmcnt(0)" ::: "memory");
        }
        pbar();
        if (t + 2 < nt) STAGE(bst, t + 2);

        short8 a[4], bb[4];
#pragma unroll
        for (int mi = 0; mi < 4; ++mi)
            a[mi] = *(const short8*)&As[bcur][(wm * 64 + mi * 16 + l16) * 32 + sw];
#pragma unroll
        for (int ni = 0; ni < 4; ++ni)
            bb[ni] = *(const short8*)&Bs[bcur][(wn * 64 + ni * 16 + l16) * 32 + sw];
#pragma unroll
        for (int mi = 0; mi < 4; ++mi)
#pragma unroll
            for (int ni = 0; ni < 4; ++ni)
                acc[mi][ni] = __builtin_amdgcn_mfma_f32_16x16x32_bf16(a[mi], bb[ni], acc[mi][ni], 0, 0, 0);

        bcur = (bcur == 2) ? 0 : bcur + 1;
        bst  = (bst == 2) ? 0 : bst + 1;
    }
#undef STAGE

    // epilogue. C/D layout: col=l16, row=quad*4+r
#pragma unroll
    for (int ni = 0; ni < 4; ++ni) {
        const int n = n0 + wn * 64 + ni * 16 + l16;
        const float bval = bias[n];
        const int seg = n >> 10;       // block-uniform (1024 % 128 == 0)
        const int nl  = n & 1023;
#pragma unroll
        for (int mi = 0; mi < 4; ++mi) {
            if constexpr (MODE == 0) {
#pragma unroll
                for (int r = 0; r < 4; ++r) {
                    const int m = m0 + wm * 64 + mi * 16 + (quad << 2) + r;
                    const float val = acc[mi][ni][r] + bval;
                    if constexpr (std::is_same<OutT, unsigned short>::value)
                        C[(size_t)m * N + n] = f2bf(val);
                    else
                        C[(size_t)m * N + n] = val;
                }
            } else {
                if (seg < 2) {
                    unsigned short* P = (seg == 0) ? Qo : Ko;
#pragma unroll
                    for (int r = 0; r < 4; ++r) {
                        const int m = m0 + wm * 64 + mi * 16 + (quad << 2) + r;
                        P[(size_t)m * 1024 + nl] = f2bf(acc[mi][ni][r] + bval);
                    }
                } else {
                    // V: 4 consecutive t -> one dwordx2 store
                    const int mb = m0 + wm * 64 + mi * 16 + (quad << 2);
                    const int bbk = mb >> 11, t0 = mb & 2047;
                    unsigned int lo = (unsigned int)f2bf(acc[mi][ni][0] + bval) |
                                      ((unsigned int)f2bf(acc[mi][ni][1] + bval) << 16);
                    unsigned int hi = (unsigned int)f2bf(acc[mi][ni][2] + bval) |
                                      ((unsigned int)f2bf(acc[mi][ni][3] + bval) << 16);
                    uint2 pv; pv.x = lo; pv.y = hi;
                    *(uint2*)(Vto + ((size_t)bbk * 1024 + nl) * 2048 + t0) = pv;
                }
            }
        }
    }
}

// softmax + bf16-pack + in-register P redistribution for one 16-q-row sub.
// s[ks][r] = S^T[key = key0 + ks*16 + kq4 + r][q-row = qg]; produces the two
// PV A-fragments pf0 (keys 0..31) / pf1 (keys 32..63) via
// permlane32_swap+permlane16_swap (see r6 derivation), accumulates row-sum.
__device__ __forceinline__ void softmax_pack(
    const floatx4* s, bool masked, int key0, int qg, int kq4,
    float& l_run, short8& pf0o, short8& pf1o)
{
    const float SC2 = 0.18033688011112042f;    // 0.125*log2(e)
    const float MB2 = -17.312340490667562f;    // -12*log2(e)
    unsigned int plo[4], phi[4];
    if (!masked) {
#pragma unroll
        for (int ks = 0; ks < 4; ++ks) {
            float pv0 = __builtin_amdgcn_exp2f(fmaf(s[ks][0], SC2, MB2));
            float pv1 = __builtin_amdgcn_exp2f(fmaf(s[ks][1], SC2, MB2));
            float pv2 = __builtin_amdgcn_exp2f(fmaf(s[ks][2], SC2, MB2));
            float pv3 = __builtin_amdgcn_exp2f(fmaf(s[ks][3], SC2, MB2));
            l_run += (pv0 + pv1) + (pv2 + pv3);
            asm("v_cvt_pk_bf16_f32 %0, %1, %2" : "=v"(plo[ks]) : "v"(pv0), "v"(pv1));
            asm("v_cvt_pk_bf16_f32 %0, %1, %2" : "=v"(phi[ks]) : "v"(pv2), "v"(pv3));
        }
    } else {
#pragma unroll
        for (int ks = 0; ks < 4; ++ks) {
            const int kb = key0 + (ks << 4) + kq4;
            float a0 = (kb + 0 <= qg) ? fmaf(s[ks][0], SC2, MB2) : -100000.0f;
            float a1 = (kb + 1 <= qg) ? fmaf(s[ks][1], SC2, MB2) : -100000.0f;
            float a2 = (kb + 2 <= qg) ? fmaf(s[ks][2], SC2, MB2) : -100000.0f;
            float a3 = (kb + 3 <= qg) ? fmaf(s[ks][3], SC2, MB2) : -100000.0f;
            float pv0 = __builtin_amdgcn_exp2f(a0);
            float pv1 = __builtin_amdgcn_exp2f(a1);
            float pv2 = __builtin_amdgcn_exp2f(a2);
            float pv3 = __builtin_amdgcn_exp2f(a3);
            l_run += (pv0 + pv1) + (pv2 + pv3);
            asm("v_cvt_pk_bf16_f32 %0, %1, %2" : "=v"(plo[ks]) : "v"(pv0), "v"(pv1));
            asm("v_cvt_pk_bf16_f32 %0, %1, %2" : "=v"(phi[ks]) : "v"(pv2), "v"(pv3));
        }
    }
    uintx2v t0 = __builtin_amdgcn_permlane32_swap(plo[0], plo[1], false, false);
    uintx2v u0 = __builtin_amdgcn_permlane16_swap(t0[0], t0[1], false, false);
    uintx2v t1 = __builtin_amdgcn_permlane32_swap(phi[0], phi[1], false, false);
    uintx2v u1 = __builtin_amdgcn_permlane16_swap(t1[0], t1[1], false, false);
    uintx2v t2 = __builtin_amdgcn_permlane32_swap(plo[2], plo[3], false, false);
    uintx2v u2 = __builtin_amdgcn_permlane16_swap(t2[0], t2[1], false, false);
    uintx2v t3 = __builtin_amdgcn_permlane32_swap(phi[2], phi[3], false, false);
    uintx2v u3 = __builtin_amdgcn_permlane16_swap(t3[0], t3[1], false, false);
    union { unsigned int d[4]; short8 v; } fa, fb;
    fa.d[0] = u0[0]; fa.d[1] = u1[0]; fa.d[2] = u0[1]; fa.d[3] = u1[1];
    fb.d[0] = u2[0]; fb.d[1] = u3[0]; fb.d[2] = u2[1]; fb.d[3] = u3[1];
    pf0o = fa.v;
    pf1o = fb.v;
}

// Flash attention (r9 structure, unchanged): 128 q-rows/block, 2x16-row subs
// per wave sharing K/V fragment registers; single-buffer 16KB LDS; balanced
// qt' permutation; fully-masked tiles skip compute.
__global__ __launch_bounds__(256, 4) void attn_kernel(
    const unsigned short* __restrict__ Q,
    const unsigned short* __restrict__ Kq,
    const unsigned short* __restrict__ Vt,
    unsigned short* __restrict__ Y)
{
    const int T = 2048;

    int idx = blockIdx.x;
    int g   = idx >> 6;              // 0..15 (16 q-tiles of 128 rows)
    int qtp = (g & 4) ? ((g & 8) ? (g - 8) : (g - 4))
                      : ((g & 8) ? (19 - g) : (15 - g));
    int bh  = idx & 63;
    int b   = bh >> 4;
    int h   = bh & 15;

    const int tid  = threadIdx.x;
    const int lane = tid & 63;
    const int w    = tid >> 6;
    const int quad = lane >> 4;
    const int l16  = lane & 15;

    __shared__ __align__(16) unsigned short Ks2[8 * 64 * 8];   // 8KB
    __shared__ __align__(16) unsigned short Vs2[8 * 64 * 8];   // 8KB

    const int qb = qtp * 128 + (w << 5);     // wave's first q row

    const unsigned short* qpa = Q + (size_t)(b * T + qb + l16) * 1024 + h * 64;
    const unsigned short* qpb = qpa + (size_t)16 * 1024;
    short8 qfa0 = *(const short8*)(qpa + (quad << 3));
    short8 qfa1 = *(const short8*)(qpa + 32 + (quad << 3));
    short8 qfb0 = *(const short8*)(qpb + (quad << 3));
    short8 qfb1 = *(const short8*)(qpb + 32 + (quad << 3));

    float lra = 0.0f, lrb = 0.0f;
    floatx4 oa[4], ob[4];
#pragma unroll
    for (int ns = 0; ns < 4; ++ns) { oa[ns] = (floatx4)0.0f; ob[ns] = (floatx4)0.0f; }

    const unsigned short* kg0p = Kq + (size_t)(b * T + lane) * 1024 + h * 64 + (w) * 8;
    const unsigned short* kg1p = Kq + (size_t)(b * T + lane) * 1024 + h * 64 + (w + 4) * 8;
    const unsigned short* vg0p = Vt + ((size_t)(b * 1024 + h * 64 + lane)) * 2048 + (w) * 8;
    const unsigned short* vg1p = Vt + ((size_t)(b * 1024 + h * 64 + lane)) * 2048 + (w + 4) * 8;

    const int qa_g = qb + l16;        // sub-a lane q
    const int qb_g = qb + 16 + l16;   // sub-b lane q
    const int kq4  = quad << 2;

    const int ktiles = 2 * qtp + 2;
    for (int kt = 0; kt < ktiles; ++kt) {
        const int key0 = kt << 6;
        __syncthreads();
        gload_lds16(kg0p + (size_t)key0 * 1024, Ks2 + (w) * 512);
        gload_lds16(kg1p + (size_t)key0 * 1024, Ks2 + (w + 4) * 512);
        gload_lds16(vg0p + key0, Vs2 + (w) * 512);
        gload_lds16(vg1p + key0, Vs2 + (w + 4) * 512);
        __syncthreads();

        if (key0 <= qb + 31) {         // wave-uniform: skip fully-masked tiles
            floatx4 sa[4], sb[4];
#pragma unroll
            for (int ks = 0; ks < 4; ++ks) {
                short8 kf0 = *(const short8*)&Ks2[((0 * 4 + quad) * 64 + ks * 16 + l16) * 8];
                short8 kf1 = *(const short8*)&Ks2[((1 * 4 + quad) * 64 + ks * 16 + l16) * 8];
                sa[ks] = __builtin_amdgcn_mfma_f32_16x16x32_bf16(kf0, qfa0, (floatx4)0.0f, 0, 0, 0);
                sa[ks] = __builtin_amdgcn_mfma_f32_16x16x32_bf16(kf1, qfa1, sa[ks], 0, 0, 0);
                sb[ks] = __builtin_amdgcn_mfma_f32_16x16x32_bf16(kf0, qfb0, (floatx4)0.0f, 0, 0, 0);
                sb[ks] = __builtin_amdgcn_mfma_f32_16x16x32_bf16(kf1, qfb1, sb[ks], 0, 0, 0);
            }

            const bool masked = (key0 + 64 > qb);   // wave-uniform
            short8 pa0, pa1, pb0, pb1;
            softmax_pack(sa, masked, key0, qa_g, kq4, lra, pa0, pa1);
            softmax_pack(sb, masked, key0, qb_g, kq4, lrb, pb0, pb1);

#pragma unroll
            for (int ns = 0; ns < 4; ++ns) {
                short8 vf0 = *(const short8*)&Vs2[((0 * 4 + quad) * 64 + ns * 16 + l16) * 8];
                short8 vf1 = *(const short8*)&Vs2[((1 * 4 + quad) * 64 + ns * 16 + l16) * 8];
                oa[ns] = __builtin_amdgcn_mfma_f32_16x16x32_bf16(pa0, vf0, oa[ns], 0, 0, 0);
                oa[ns] = __builtin_amdgcn_mfma_f32_16x16x32_bf16(pa1, vf1, oa[ns], 0, 0, 0);
                ob[ns] = __builtin_amdgcn_mfma_f32_16x16x32_bf16(pb0, vf0, ob[ns], 0, 0, 0);
                ob[ns] = __builtin_amdgcn_mfma_f32_16x16x32_bf16(pb1, vf1, ob[ns], 0, 0, 0);
            }
        }
    }

    float sa_ = lra;
    sa_ += __shfl_xor(sa_, 16, 64);
    sa_ += __shfl_xor(sa_, 32, 64);
    const float lia = 1.0f / sa_;
    float sb_ = lrb;
    sb_ += __shfl_xor(sb_, 16, 64);
    sb_ += __shfl_xor(sb_, 32, 64);
    const float lib = 1.0f / sb_;

    float la[4], lb[4];
#pragma unroll
    for (int r = 0; r < 4; ++r) {
        la[r] = __shfl(lia, (quad << 2) + r, 64);
        lb[r] = __shfl(lib, (quad << 2) + r, 64);
    }

#pragma unroll
    for (int ns = 0; ns < 4; ++ns) {
        int d = (ns << 4) + l16;
#pragma unroll
        for (int r = 0; r < 4; ++r) {
            int ta = qb + (quad << 2) + r;
            Y[(size_t)(b * T + ta) * 1024 + h * 64 + d]        = f2bf(oa[ns][r] * la[r]);
            Y[(size_t)(b * T + ta + 16) * 1024 + h * 64 + d]   = f2bf(ob[ns][r] * lb[r]);
        }
    }
}

extern "C" void kernel_launch(void* const* d_in, const int* in_sizes, int n_in,
                              void* d_out, int out_size, void* d_ws, size_t ws_size,
                              hipStream_t stream) {
    const float* x  = (const float*)d_in[0];  // [4,2048,1024] fp32
    const float* Wa = (const float*)d_in[1];  // [1024,3072]  fp32
    const float* ba = (const float*)d_in[2];  // [3072]       fp32
    const float* Wp = (const float*)d_in[3];  // [1024,1024]  fp32
    const float* bp = (const float*)d_in[4];  // [1024]       fp32
    float* out = (float*)d_out;               // [4,2048,1024] fp32

    const size_t NX = (size_t)8192 * 1024;

    unsigned short* Qb  = (unsigned short*)d_ws;         // 8192*1024
    unsigned short* Kb  = Qb  + NX;                      // 8192*1024
    unsigned short* Vtb = Kb  + NX;                      // 4096*2048 = 8192*1024
    unsigned short* Yb  = Vtb + NX;                      // 8192*1024
    unsigned short* xb  = Yb  + NX;                      // 8192*1024
    unsigned short* Wat = xb  + NX;                      // 3072*1024 (N-major)
    unsigned short* Wpt = Wat + (size_t)3072 * 1024;     // 1024*1024

    // 0) convert x; transpose+convert weights to [N][K] bf16
    cvt_f32_bf16_kernel<<<(int)(NX / 8 / 256), 256, 0, stream>>>(x, xb, (int)(NX / 8));
    transpose_cvt_kernel<<<dim3(3072 / 32, 1024 / 32), 256, 0, stream>>>(Wa, Wat, 1024, 3072);
    transpose_cvt_kernel<<<dim3(1024 / 32, 1024 / 32), 256, 0, stream>>>(Wp, Wpt, 1024, 1024);

    // 1) qkv = x @ W_attn + b_attn -> Q,K ([m][1024]) and V transposed ([b*1024+d][2048])
    gemm128_kernel<1, unsigned short><<<dim3(3072 / 128, 8192 / 128), 256, 0, stream>>>(
        xb, Wat, ba, (unsigned short*)nullptr, Qb, Kb, Vtb, 8192, 3072, 1024);

    // 2) flash attention -> Y [B,T,C] bf16 (128-q-row blocks, 2 subs/wave)
    attn_kernel<<<4 * 16 * (2048 / 128), 256, 0, stream>>>(Qb, Kb, Vtb, Yb);

    // 3) out = Y @ W_proj + b_proj (fp32)
    gemm128_kernel<0, float><<<dim3(1024 / 128, 8192 / 128), 256, 0, stream>>>(
        Yb, Wpt, bp, out, nullptr, nullptr, nullptr, 8192, 1024, 1024);
}